// Round 7
// baseline (968.780 us; speedup 1.0000x reference)
//
#include <hip/hip_runtime.h>
#include <math.h>

#define NN 40000
#define EE 640000
#define DD 128
#define EDD 16
#define LL 3
#define CH 32   // edges per wave in edge_msg_kernel

__device__ __constant__ float kBnInv = 0.9999950000374997f; // 1/sqrt(1+1e-5)

typedef __bf16 bf16x8 __attribute__((ext_vector_type(8)));
typedef float  f32x4  __attribute__((ext_vector_type(4)));

// pack two floats to bf16 pair (RTNE) in one uint: lo16=a, hi16=b
__device__ __forceinline__ unsigned pack_bf2(float a, float b) {
    unsigned ua = __float_as_uint(a), ub = __float_as_uint(b);
    ua = (ua + 0x7fffu + ((ua >> 16) & 1u)) >> 16;
    ub = (ub + 0x7fffu + ((ub >> 16) & 1u)) & 0xffff0000u;
    return ua | ub;
}
__device__ __forceinline__ unsigned short bf16r(float x) {
    unsigned u = __float_as_uint(x);
    u = (u + 0x7fffu + ((u >> 16) & 1u)) >> 16;
    return (unsigned short)u;
}

// ---------------------------------------------------------------------------
// h = x @ node_W + node_b; also emits packed-bf16 hb
__global__ __launch_bounds__(256) void node_enc_kernel(
    const float* __restrict__ x, const float* __restrict__ W,
    const float* __restrict__ b, float* __restrict__ h,
    unsigned* __restrict__ hb)
{
    __shared__ float xs[32][DD];
    const int t = threadIdx.x;
    const long rowbase = (long)blockIdx.x * 32;

    const float4* x4 = (const float4*)(x + rowbase * DD);
    float4* xs4 = (float4*)&xs[0][0];
#pragma unroll
    for (int i = 0; i < 4; i++) xs4[t + i * 256] = x4[t + i * 256];
    __syncthreads();

    const int c  = (t & 31) * 4;
    const int r0 = (t >> 5) * 4;

    float acc[4][4] = {};
    for (int k4 = 0; k4 < DD; k4 += 4) {
        float4 xr[4];
#pragma unroll
        for (int i = 0; i < 4; i++) xr[i] = *(const float4*)&xs[r0 + i][k4];
#pragma unroll
        for (int kk = 0; kk < 4; kk++) {
            const float4 w = *(const float4*)(W + (k4 + kk) * DD + c);
#pragma unroll
            for (int i = 0; i < 4; i++) {
                const float xv = ((const float*)&xr[i])[kk];
                acc[i][0] = fmaf(xv, w.x, acc[i][0]);
                acc[i][1] = fmaf(xv, w.y, acc[i][1]);
                acc[i][2] = fmaf(xv, w.z, acc[i][2]);
                acc[i][3] = fmaf(xv, w.w, acc[i][3]);
            }
        }
    }
    const float4 bv = *(const float4*)(b + c);
#pragma unroll
    for (int i = 0; i < 4; i++) {
        const long row = rowbase + r0 + i;
        float4 ov = { acc[i][0] + bv.x, acc[i][1] + bv.y,
                      acc[i][2] + bv.z, acc[i][3] + bv.w };
        *(float4*)(h + row * DD + c) = ov;
        uint2 pv = { pack_bf2(ov.x, ov.y), pack_bf2(ov.z, ov.w) };
        *(uint2*)(hb + row * 64 + (c >> 1)) = pv;
    }
}

// ---------------------------------------------------------------------------
// weight transpose + bf16 cast: w1t[l][n][k] = W1[l][k][n]; w2t[l][n][k] = W2[l][k][n]
__global__ __launch_bounds__(256) void wcast_kernel(
    const float* __restrict__ W1, const float* __restrict__ W2,
    unsigned short* __restrict__ w1t, unsigned short* __restrict__ w2t)
{
    const int idx = blockIdx.x * 256 + threadIdx.x;   // grid covers LL*32768
    const int l = idx >> 15, r = idx & 32767;
    {   const int n = r >> 7, k = r & 127;            // n<256, k<128
        w1t[idx] = bf16r(W1[(l << 15) + (k << 8) + n]);
    }
    {   const int n = r >> 8, k = r & 255;            // n<128, k<256
        w2t[idx] = bf16r(W2[(l << 15) + (k << 7) + n]);
    }
}

// ---------------------------------------------------------------------------
// CSR build
__global__ __launch_bounds__(256) void hist_kernel(
    const int* __restrict__ edge_index, int* __restrict__ counts)
{
    const int i = blockIdx.x * 256 + threadIdx.x;
    atomicAdd(&counts[edge_index[EE + i]], 1);
}

__global__ __launch_bounds__(256) void scan1_kernel(
    const int* __restrict__ counts, int* __restrict__ scanned,
    int* __restrict__ partials)
{
    __shared__ int sdata[256];
    const int t = threadIdx.x;
    const int base = blockIdx.x * 1024 + t * 4;
    int v[4]; int sum = 0;
#pragma unroll
    for (int i = 0; i < 4; i++) {
        const int idx = base + i;
        v[i] = (idx < NN) ? counts[idx] : 0;
        sum += v[i];
    }
    sdata[t] = sum;
    __syncthreads();
    for (int off = 1; off < 256; off <<= 1) {
        int x = (t >= off) ? sdata[t - off] : 0;
        __syncthreads();
        sdata[t] += x;
        __syncthreads();
    }
    int run = sdata[t] - sum;
#pragma unroll
    for (int i = 0; i < 4; i++) {
        const int idx = base + i;
        if (idx < NN) scanned[idx] = run;
        run += v[i];
    }
    if (t == 255) partials[blockIdx.x] = sdata[255];
}

__global__ void scan2_kernel(int* __restrict__ partials)
{
    if (threadIdx.x == 0) {
        int run = 0;
        for (int i = 0; i < 40; i++) { int v = partials[i]; partials[i] = run; run += v; }
    }
}

__global__ __launch_bounds__(256) void scan3_kernel(
    const int* __restrict__ scanned, const int* __restrict__ partials,
    int* __restrict__ offsets, int* __restrict__ cursor)
{
    const int idx = blockIdx.x * 256 + threadIdx.x;
    if (idx < NN) {
        const int off = scanned[idx] + partials[idx >> 10];
        offsets[idx] = off;
        cursor[idx]  = off;
    }
}

// writes perm + pre-scaled src/dst streams (src*64 = hb row, dst*128 = z row)
__global__ __launch_bounds__(256) void scatter_kernel(
    const int* __restrict__ edge_index, int* __restrict__ cursor,
    int* __restrict__ perm, int* __restrict__ srcs_p, int* __restrict__ dstd_p)
{
    const int i = blockIdx.x * 256 + threadIdx.x;
    const int src = edge_index[i];
    const int dst = edge_index[EE + i];
    const int pos = atomicAdd(&cursor[dst], 1);
    perm[pos] = i;
    srcs_p[pos] = src << 6;
    dstd_p[pos] = dst << 7;
}

__global__ __launch_bounds__(256) void ea_perm_kernel(
    const float* __restrict__ edge_attr, const int* __restrict__ perm,
    float* __restrict__ ea_p)
{
    const int pos = blockIdx.x * 256 + threadIdx.x;
    const int e = perm[pos];
    const float4* sp = (const float4*)(edge_attr + (long)e * EDD);
    float4* dp = (float4*)(ea_p + (long)pos * EDD);
    dp[0] = sp[0]; dp[1] = sp[1]; dp[2] = sp[2]; dp[3] = sp[3];
}

// ---------------------------------------------------------------------------
// per-node attention partials + z init (z = (1+eps)*h)
__global__ __launch_bounds__(256) void attn_pre_kernel(
    const float* __restrict__ h, const float* __restrict__ aW,
    const float* __restrict__ eps_p,
    float* __restrict__ pi, float* __restrict__ pj, float* __restrict__ z)
{
    const int wid  = threadIdx.x >> 6;
    const int lane = threadIdx.x & 63;
    const int n = blockIdx.x * 4 + wid;
    const int c0 = lane, c1 = lane + 64;
    const float ep = 1.0f + eps_p[0];
    const float h0 = h[(long)n * DD + c0], h1 = h[(long)n * DD + c1];

    z[(long)n * DD + c0] = ep * h0;
    z[(long)n * DD + c1] = ep * h1;

    float a = h0 * aW[c0]      + h1 * aW[c1];
    float b = h0 * aW[DD + c0] + h1 * aW[DD + c1];
#pragma unroll
    for (int off = 32; off > 0; off >>= 1) {
        a += __shfl_xor(a, off, 64);
        b += __shfl_xor(b, off, 64);
    }
    if (lane == 0) { pi[n] = a; pj[n] = b; }
}

// per-edge attention coefficient (streams are pre-scaled; shift back)
__global__ __launch_bounds__(256) void attn_edge_kernel(
    const float* __restrict__ pi, const float* __restrict__ pj,
    const int* __restrict__ srcs_p, const int* __restrict__ dstd_p,
    const float* __restrict__ ab_p, float* __restrict__ a_p)
{
    const int idx = blockIdx.x * 256 + threadIdx.x;
    const float s = pi[dstd_p[idx] >> 7] + pj[srcs_p[idx] >> 6] + ab_p[0];
    a_p[idx] = 1.0f / (1.0f + expf(-s));
}

// ---------------------------------------------------------------------------
// edge embedding for 4 edges (raw loads + FMA chain)
__device__ __forceinline__ void ev4(
    const float4* __restrict__ eap,
    const float* __restrict__ ew0, const float* __restrict__ ew1,
    float eb0, float eb1, float* ev0, float* ev1)
{
#pragma unroll
    for (int j = 0; j < 4; j++) {
        const float4 t0 = eap[j*4+0], t1 = eap[j*4+1],
                     t2 = eap[j*4+2], t3 = eap[j*4+3];
        const float ea[EDD] = { t0.x,t0.y,t0.z,t0.w, t1.x,t1.y,t1.z,t1.w,
                                t2.x,t2.y,t2.z,t2.w, t3.x,t3.y,t3.z,t3.w };
        float s0 = eb0, s1 = eb1;
#pragma unroll
        for (int q = 0; q < EDD; q++) {
            s0 = fmaf(ea[q], ew0[q], s0);
            s1 = fmaf(ea[q], ew1[q], s1);
        }
        ev0[j] = s0; ev1[j] = s1;
    }
}

// Edge-parallel segmented aggregation, cross-batch software pipeline:
// iter b: issue gathers(b+1), issue streams(b+2), compute ev(b+1), consume(b).
// streams pre-scaled; z pre-initialized to (1+eps)*h.
__global__ __launch_bounds__(256) void edge_msg_kernel(
    const unsigned* __restrict__ hb, const float* __restrict__ ea_p,
    const float* __restrict__ a_p,
    const int* __restrict__ srcs_p, const int* __restrict__ dstd_p,
    const float* __restrict__ eW, const float* __restrict__ eb,
    float* __restrict__ z)
{
    const int wid  = threadIdx.x >> 6;
    const int lane = threadIdx.x & 63;
    const long e0  = ((long)blockIdx.x * 4 + wid) * CH;  // grid = EE/(4*CH)
    const int c0 = lane * 2, c1 = c0 + 1;

    float ew0[EDD], ew1[EDD];
#pragma unroll
    for (int q = 0; q < EDD; q++) {
        const float2 w2 = ((const float2*)(eW + q * DD))[lane];
        ew0[q] = w2.x; ew1[q] = w2.y;
    }
    const float2 eb2 = ((const float2*)eb)[lane];
    const float eb0 = eb2.x, eb1 = eb2.y;

    float acc0 = 0.0f, acc1 = 0.0f;

    // prologue: streams(0),(1); gathers(0); ev(0)
    int4   sS0 = *(const int4*)(srcs_p + e0);
    int4   sD0 = *(const int4*)(dstd_p + e0);
    float4 sA0 = *(const float4*)(a_p + e0);
    int4   sS1 = *(const int4*)(srcs_p + e0 + 4);
    int4   sD1 = *(const int4*)(dstd_p + e0 + 4);
    float4 sA1 = *(const float4*)(a_p + e0 + 4);

    unsigned u0x = hb[sS0.x + lane], u0y = hb[sS0.y + lane],
             u0z = hb[sS0.z + lane], u0w = hb[sS0.w + lane];

    float evA0[4], evA1[4];
    ev4((const float4*)(ea_p + e0 * EDD), ew0, ew1, eb0, eb1, evA0, evA1);

    int cur = sD0.x;

#define CONSUME(u, d, a, eva, evb)                                        \
    {                                                                     \
        if ((d) != cur) {                                                 \
            atomicAdd(&z[cur + c0], acc0);                                \
            atomicAdd(&z[cur + c1], acc1);                                \
            acc0 = 0.0f; acc1 = 0.0f; cur = (d);                          \
        }                                                                 \
        const float xa = __uint_as_float((u) << 16);                      \
        const float xb = __uint_as_float((u) & 0xffff0000u);              \
        acc0 += fmaxf(fmaf(xa, (a), (eva)), 0.0f);                        \
        acc1 += fmaxf(fmaf(xb, (a), (evb)), 0.0f);                        \
    }

    const int NB = CH / 4;
#pragma unroll 2
    for (int b = 0; b < NB; b++) {
        // phase 1: gathers for batch b+1 (addresses resident since last iter)
        const unsigned u1x = hb[sS1.x + lane];
        const unsigned u1y = hb[sS1.y + lane];
        const unsigned u1z = hb[sS1.z + lane];
        const unsigned u1w = hb[sS1.w + lane];
        // phase 2: streams for batch b+2 (clamped, sequential)
        long e2 = e0 + (long)(b + 2) * 4;
        if (e2 > (long)EE - 4) e2 = (long)EE - 4;
        const int4   sS2 = *(const int4*)(srcs_p + e2);
        const int4   sD2 = *(const int4*)(dstd_p + e2);
        const float4 sA2 = *(const float4*)(a_p + e2);
        // phase 3: ev for batch b+1 (clamped; waits only on its own ea loads)
        long e1 = e0 + (long)(b + 1) * 4;
        if (e1 > (long)EE - 4) e1 = (long)EE - 4;
        float evB0[4], evB1[4];
        ev4((const float4*)(ea_p + e1 * EDD), ew0, ew1, eb0, eb1, evB0, evB1);
        // phase 4: consume batch b
        CONSUME(u0x, sD0.x, sA0.x, evA0[0], evA1[0]);
        CONSUME(u0y, sD0.y, sA0.y, evA0[1], evA1[1]);
        CONSUME(u0z, sD0.z, sA0.z, evA0[2], evA1[2]);
        CONSUME(u0w, sD0.w, sA0.w, evA0[3], evA1[3]);
        // rotate
        sS0 = sS1; sD0 = sD1; sA0 = sA1;
        sS1 = sS2; sD1 = sD2; sA1 = sA2;
        u0x = u1x; u0y = u1y; u0z = u1z; u0w = u1w;
#pragma unroll
        for (int j = 0; j < 4; j++) { evA0[j] = evB0[j]; evA1[j] = evB1[j]; }
    }
    atomicAdd(&z[cur + c0], acc0);
    atomicAdd(&z[cur + c1], acc1);
#undef CONSUME
}

// ---------------------------------------------------------------------------
// Fused GIN MLP via bf16 MFMA. Block = 64 rows, 4 waves; wave owns a 16-row
// stripe. A-frags: lane m=lane&15, k=quad*8+j; B pre-transposed [n][k] bf16.
// C/D: col=lane&15, row=quad*4+reg.
__global__ __launch_bounds__(256) void mlp_mfma_kernel(
    const float* __restrict__ zin,
    const unsigned short* __restrict__ w1t, const unsigned short* __restrict__ w2t,
    const float* __restrict__ b1, const float* __restrict__ g1, const float* __restrict__ bb1,
    const float* __restrict__ b2, const float* __restrict__ g2, const float* __restrict__ bb2,
    float* __restrict__ out, unsigned* __restrict__ hb, const int do_relu)
{
    __shared__ __align__(16) unsigned short zsb[64][136];   // 128 + 8 pad
    __shared__ __align__(16) unsigned short usb[64][264];   // 256 + 8 pad
    const int t = threadIdx.x;
    const int wid = t >> 6, lane = t & 63;
    const long rowbase = (long)blockIdx.x * 64;

    // stage z (fp32) -> zsb (bf16)
    {
        const float4* z4 = (const float4*)(zin + rowbase * DD);
#pragma unroll
        for (int i = 0; i < 8; i++) {
            const int idx = t + i * 256;          // 2048 float4 = 64x128
            const float4 v = z4[idx];
            const int row = idx >> 5;
            const int c4  = (idx & 31) * 4;
            uint2 pv = { pack_bf2(v.x, v.y), pack_bf2(v.z, v.w) };
            *(uint2*)&zsb[row][c4] = pv;
        }
    }
    __syncthreads();

    const int mrow  = lane & 15;
    const int quad  = lane >> 4;
    const int mbase = wid * 16;
    const f32x4 vzero = {0.0f, 0.0f, 0.0f, 0.0f};

    // phase 1: C1[16 x 256] = z_tile @ W1
    bf16x8 af[4];
#pragma unroll
    for (int ks = 0; ks < 4; ks++)
        af[ks] = *(const bf16x8*)&zsb[mbase + mrow][ks * 32 + quad * 8];

    f32x4 acc[16];
#pragma unroll
    for (int i = 0; i < 16; i++) acc[i] = vzero;

#pragma unroll
    for (int nt = 0; nt < 16; nt++) {
        const unsigned short* wp = w1t + (nt * 16 + mrow) * 128 + quad * 8;
#pragma unroll
        for (int ks = 0; ks < 4; ks++) {
            const bf16x8 bfr = *(const bf16x8*)(wp + ks * 32);
            acc[nt] = __builtin_amdgcn_mfma_f32_16x16x32_bf16(af[ks], bfr, acc[nt], 0, 0, 0);
        }
    }

    // epilogue 1: bn1 + relu -> usb (bf16, packed pairwise via shuffle)
#pragma unroll
    for (int nt = 0; nt < 16; nt++) {
        const int c = nt * 16 + mrow;
        const float g = g1[c], bi = b1[c], bt = bb1[c];
#pragma unroll
        for (int r = 0; r < 4; r++) {
            const int row = mbase + quad * 4 + r;
            const float u = fmaxf(fmaf(g * (acc[nt][r] + bi), kBnInv, bt), 0.0f);
            const float up = __shfl_xor(u, 1, 64);
            if ((mrow & 1) == 0)
                *(unsigned*)&usb[row][c] = pack_bf2(u, up);
        }
    }
    __syncthreads();

    // phase 2: C2[16 x 128] = u_tile @ W2
    bf16x8 af2[8];
#pragma unroll
    for (int ks = 0; ks < 8; ks++)
        af2[ks] = *(const bf16x8*)&usb[mbase + mrow][ks * 32 + quad * 8];

    f32x4 acc2[8];
#pragma unroll
    for (int i = 0; i < 8; i++) acc2[i] = vzero;

#pragma unroll
    for (int nt = 0; nt < 8; nt++) {
        const unsigned short* wp = w2t + (nt * 16 + mrow) * 256 + quad * 8;
#pragma unroll
        for (int ks = 0; ks < 8; ks++) {
            const bf16x8 bfr = *(const bf16x8*)(wp + ks * 32);
            acc2[nt] = __builtin_amdgcn_mfma_f32_16x16x32_bf16(af2[ks], bfr, acc2[nt], 0, 0, 0);
        }
    }

    // epilogue 2: bn2 (+relu) -> out fp32 + hb bf16
#pragma unroll
    for (int nt = 0; nt < 8; nt++) {
        const int c = nt * 16 + mrow;
        const float g = g2[c], bi = b2[c], bt = bb2[c];
#pragma unroll
        for (int r = 0; r < 4; r++) {
            const long row = rowbase + mbase + quad * 4 + r;
            float v = fmaf(g * (acc2[nt][r] + bi), kBnInv, bt);
            if (do_relu) v = fmaxf(v, 0.0f);
            out[row * DD + c] = v;
            const float vp = __shfl_xor(v, 1, 64);
            if ((mrow & 1) == 0)
                hb[row * 64 + (c >> 1)] = pack_bf2(v, vp);
        }
    }
}

// ---------------------------------------------------------------------------
extern "C" void kernel_launch(void* const* d_in, const int* in_sizes, int n_in,
                              void* d_out, int out_size, void* d_ws, size_t ws_size,
                              hipStream_t stream)
{
    const float* x         = (const float*)d_in[0];
    const float* edge_attr = (const float*)d_in[1];
    const float* node_W    = (const float*)d_in[2];
    const float* node_b    = (const float*)d_in[3];
    const float* edge_W    = (const float*)d_in[4];
    const float* edge_b    = (const float*)d_in[5];
    const float* attn_W    = (const float*)d_in[6];
    const float* attn_b    = (const float*)d_in[7];
    const float* eps       = (const float*)d_in[8];
    const float* W1        = (const float*)d_in[9];
    const float* b1        = (const float*)d_in[10];
    const float* bn1_g     = (const float*)d_in[11];
    const float* bn1_b     = (const float*)d_in[12];
    const float* W2        = (const float*)d_in[13];
    const float* b2        = (const float*)d_in[14];
    const float* bn_g      = (const float*)d_in[15];
    const float* bn_b      = (const float*)d_in[16];
    const int*   edge_index= (const int*)d_in[17];

    float* h    = (float*)d_ws;                          // [N*D]
    float* z    = h + (size_t)NN * DD;                   // [N*D]
    float* pi   = z + (size_t)NN * DD;                   // [N]
    float* pj   = pi + NN;                               // [N]
    float* a_p  = pj + NN;                               // [E]
    float* ea_p = a_p + EE;                              // [E*16]
    unsigned* hbuf = (unsigned*)(ea_p + (size_t)EE * EDD);          // [N*64]
    unsigned short* w1t = (unsigned short*)(hbuf + (size_t)NN * 64); // [L*256*128]
    unsigned short* w2t = w1t + (size_t)LL * 32768;                  // [L*128*256]
    int* counts  = (int*)(w2t + (size_t)LL * 32768);     // [N]
    int* offsets = counts + NN;                          // [N]
    int* cursor  = offsets + NN;                         // [N]
    int* scanned = cursor + NN;                          // [40960]
    int* partials= scanned + 40960;                      // [64]
    int* perm    = partials + 64;                        // [E]
    int* srcs_p  = perm + EE;                            // [E] (src*64)
    int* dstd_p  = srcs_p + EE;                          // [E] (dst*128)
    float* out = (float*)d_out;

    node_enc_kernel<<<NN / 32, 256, 0, stream>>>(x, node_W, node_b, h, hbuf);
    wcast_kernel<<<LL * 128, 256, 0, stream>>>(W1, W2, w1t, w2t);

    hipMemsetAsync(counts, 0, NN * sizeof(int), stream);
    hist_kernel<<<EE / 256, 256, 0, stream>>>(edge_index, counts);
    scan1_kernel<<<40, 256, 0, stream>>>(counts, scanned, partials);
    scan2_kernel<<<1, 64, 0, stream>>>(partials);
    scan3_kernel<<<(NN + 255) / 256, 256, 0, stream>>>(scanned, partials, offsets, cursor);
    scatter_kernel<<<EE / 256, 256, 0, stream>>>(edge_index, cursor, perm, srcs_p, dstd_p);
    ea_perm_kernel<<<EE / 256, 256, 0, stream>>>(edge_attr, perm, ea_p);

    for (int l = 0; l < LL; l++) {
        attn_pre_kernel<<<NN / 4, 256, 0, stream>>>(
            h, attn_W + (size_t)l * 2 * DD, eps + l, pi, pj, z);
        attn_edge_kernel<<<EE / 256, 256, 0, stream>>>(
            pi, pj, srcs_p, dstd_p, attn_b + l, a_p);
        edge_msg_kernel<<<EE / (4 * CH), 256, 0, stream>>>(
            hbuf, ea_p, a_p, srcs_p, dstd_p,
            edge_W + (size_t)l * EDD * DD, edge_b + (size_t)l * DD, z);
        mlp_mfma_kernel<<<NN / 64, 256, 0, stream>>>(
            z,
            w1t + (size_t)l * 32768, w2t + (size_t)l * 32768,
            b1 + (size_t)l * 2 * DD, bn1_g + (size_t)l * 2 * DD, bn1_b + (size_t)l * 2 * DD,
            b2 + (size_t)l * DD, bn_g + (size_t)l * DD, bn_b + (size_t)l * DD,
            (l == LL - 1) ? out : h, hbuf, (l < LL - 1) ? 1 : 0);
    }
}